// Round 5
// baseline (986.595 us; speedup 1.0000x reference)
//
#include <hip/hip_runtime.h>
#include <math.h>

// ---------------- problem constants ----------------
#define H_   12
#define NRR  512
#define N_   768
#define C1_  384
#define C2_  128
static __device__ __constant__ float WC_  = 0.2357022603955158f;   // sqrt(2/(9*4))
static __device__ __constant__ float SC1_ = 0.14433756729740646f;  // sqrt(1/3)/sqrt(16)

// ---------------- workspace layout (float offsets), ~75.7 MiB ----------------
#define OFF_Q1     0            // [768][12][16]
#define OFF_QP     147456       // [768][12][12]
#define OFF_V1     258048       // [768][12][16]
#define OFF_VP     405504       // [768][3][96]   ([j][d][h*8+p])
#define OFF_R      626688       // [768][9]
#define OFF_T      633600       // [768][3]
#define OFF_KHAT   635904       // [12][768][32]  (0..15 k1, 16..27 kp)
#define OFF_WFRAG  930816       // 4 mats x 4 ks x 64 lanes x 8 bf16 (as 4096 floats)
#define OFF_QKF    934912       // [768*12 tiles][4 w][64 lane][4 reg] f32
#define OFF_MUSED  10372096     // [768][12 tiles][16 h]
#define OFF_MSFIN  10519552     // [768][32]: m_fin[16], s_fin[16]
#define OFF_W      10544128     // [768][12 h][768 j]  unnormalized e (f32)
#define OFF_FEAT   17622016     // [768][2112]
#define OFF_PART   19244032     // [2][768][384]

typedef __attribute__((ext_vector_type(8))) short short8_m;
typedef __attribute__((ext_vector_type(4))) float f32x4_m;

__device__ __forceinline__ ushort f2bf(float f) {
  uint u = __float_as_uint(f);
  uint r = (u + 0x7fffu + ((u >> 16) & 1u)) >> 16;
  return (ushort)r;
}
__device__ __forceinline__ float bf2f(ushort v) {
  return __uint_as_float(((uint)v) << 16);
}

// ================= kernel A: per-token projections =================
__global__ __launch_bounds__(192) void proj_kernel(
    const float* __restrict__ rec_1d, const float* __restrict__ lig_1d,
    const float* __restrict__ rec_T,  const float* __restrict__ lig_T,
    const float* __restrict__ rec_w1d, const float* __restrict__ rec_wpt,
    const float* __restrict__ lig_w1d, const float* __restrict__ lig_wpt,
    float* __restrict__ ws) {
  const int tok0 = blockIdx.x * 4;
  const int tid  = threadIdx.x;       // 0..191
  __shared__ float xs[4][384];
  __shared__ float loc[4][576];
  __shared__ float Rs[4][9];
  __shared__ float tts[4][3];

  for (int r = 0; r < 4; ++r) {
    int n = tok0 + r;
    const float* x = (n < NRR) ? rec_1d + n * C1_ : lig_1d + (n - NRR) * C1_;
    for (int k = tid; k < C1_; k += 192) xs[r][k] = x[k];
  }
  if (tid < 4) {
    int n = tok0 + tid;
    const float* T = (n < NRR) ? rec_T + n * 7 : lig_T + (n - NRR) * 7;
    float qw = T[0], qx = T[1], qy = T[2], qz = T[3];
    float inv = 1.0f / sqrtf(qw*qw + qx*qx + qy*qy + qz*qz);
    qw *= inv; qx *= inv; qy *= inv; qz *= inv;
    Rs[tid][0] = 1.f - 2.f*(qy*qy + qz*qz);
    Rs[tid][1] = 2.f*(qx*qy - qw*qz);
    Rs[tid][2] = 2.f*(qx*qz + qw*qy);
    Rs[tid][3] = 2.f*(qx*qy + qw*qz);
    Rs[tid][4] = 1.f - 2.f*(qx*qx + qz*qz);
    Rs[tid][5] = 2.f*(qy*qz - qw*qx);
    Rs[tid][6] = 2.f*(qx*qz - qw*qy);
    Rs[tid][7] = 2.f*(qy*qz + qw*qx);
    Rs[tid][8] = 1.f - 2.f*(qx*qx + qy*qy);
    tts[tid][0] = T[4]; tts[tid][1] = T[5]; tts[tid][2] = T[6];
    float* Rg = ws + OFF_R + n * 9;
    #pragma unroll
    for (int k = 0; k < 9; ++k) Rg[k] = Rs[tid][k];
    float* tg = ws + OFF_T + n * 3;
    tg[0] = T[4]; tg[1] = T[5]; tg[2] = T[6];
  }
  __syncthreads();

  const float* w1 = (tok0 < NRR) ? rec_w1d : lig_w1d;
  const float* w2 = (tok0 < NRR) ? rec_wpt : lig_wpt;
  for (int cc = 0; cc < 3; ++cc) {
    int c = tid + cc * 192;
    float a0=0,a1=0,a2=0,a3=0,b0=0,b1=0,b2=0,b3=0;
    for (int k = 0; k < C1_; ++k) {
      float wv = w1[k * 576 + c];
      float wp = w2[k * 576 + c];
      float x0 = xs[0][k], x1 = xs[1][k], x2 = xs[2][k], x3 = xs[3][k];
      a0 += x0*wv; a1 += x1*wv; a2 += x2*wv; a3 += x3*wv;
      b0 += x0*wp; b1 += x1*wp; b2 += x2*wp; b3 += x3*wp;
    }
    loc[0][c]=b0; loc[1][c]=b1; loc[2][c]=b2; loc[3][c]=b3;
    int h = c / 48, e = c % 48;
    float av[4] = {a0,a1,a2,a3};
    for (int r = 0; r < 4; ++r) {
      int n = tok0 + r;
      if (e < 16)      ws[OFF_KHAT + ((size_t)h*N_ + n)*32 + e] = av[r];
      else if (e < 32) ws[OFF_Q1 + n*192 + h*16 + (e-16)]       = av[r];
      else             ws[OFF_V1 + n*192 + h*16 + (e-32)]       = av[r];
    }
  }
  __syncthreads();

  {
    int cp = tid;                 // 0..191
    int h = cp >> 4, e = cp & 15;
    for (int r = 0; r < 4; ++r) {
      int n = tok0 + r;
      float g[3];
      #pragma unroll
      for (int d = 0; d < 3; ++d)
        g[d] = Rs[r][d*3+0]*loc[r][cp] + Rs[r][d*3+1]*loc[r][192+cp]
             + Rs[r][d*3+2]*loc[r][384+cp] + tts[r][d];
      if (e < 4) {
        #pragma unroll
        for (int d = 0; d < 3; ++d)
          ws[OFF_KHAT + ((size_t)h*N_ + n)*32 + 16 + e*3 + d] = g[d];
      } else if (e < 8) {
        #pragma unroll
        for (int d = 0; d < 3; ++d) ws[OFF_QP + n*144 + h*12 + (e-4)*3 + d] = g[d];
      } else {
        #pragma unroll
        for (int d = 0; d < 3; ++d) ws[OFF_VP + n*288 + d*96 + h*8 + (e-8)] = g[d];
      }
    }
  }
}

// ============ kernel W: build bf16 MFMA B-fragments of the 4 bias weights ============
// layout: [mat][ks][lane][8 bf16]; element = W_mat[k*12 + n], n=lane&15 (0 if n>=12),
// k = ks*32 + (lane>>4)*8 + e.
__global__ __launch_bounds__(256) void wfrag_kernel(
    const float* __restrict__ rr_w, const float* __restrict__ rl_w,
    const float* __restrict__ lr_w, const float* __restrict__ ll_w,
    float* __restrict__ ws) {
  ushort* wf = (ushort*)(ws + OFF_WFRAG);
  const float* mats[4] = { rr_w, rl_w, lr_w, ll_w };
  for (int idx = threadIdx.x; idx < 8192; idx += 256) {
    int mat = idx >> 11;
    int r   = idx & 2047;
    int ks  = r >> 9;
    int r2  = r & 511;
    int l   = r2 >> 3;
    int e   = r2 & 7;
    int n   = l & 15;
    int k   = ks*32 + (l>>4)*8 + e;
    float v = (n < 12) ? mats[mat][k*12 + n] : 0.f;
    wf[idx] = f2bf(v);
  }
}

// ============ kernel QK: scalar-q·k + point-distance terms, fragment-ordered ============
// grid: 768*12 (i, tile). thread: w = t>>6 (M-tile), lane l: h=l&15, jq=l>>4; 4 regs.
__global__ __launch_bounds__(256) void qk_kernel(float* __restrict__ ws) {
  const int b = blockIdx.x;
  const int i = b / 12, tile = b % 12;
  const int t = threadIdx.x;
  const int l = t & 63, w = t >> 6;
  __shared__ float q1s[12][16];
  __shared__ float qps[12][12];
  if (t < 192) q1s[t >> 4][t & 15] = ws[OFF_Q1 + i*192 + t];
  if (t < 144) qps[t / 12][t % 12] = ws[OFF_QP + i*144 + t];
  __syncthreads();
  const int h = l & 15, jq = l >> 4;
  float val[4] = {0.f, 0.f, 0.f, 0.f};
  if (h < 12) {
    #pragma unroll
    for (int rr = 0; rr < 4; ++rr) {
      int j = tile*64 + w*16 + jq*4 + rr;
      const float* kf = ws + OFF_KHAT + ((size_t)h*N_ + j)*32;
      float kv[28];
      #pragma unroll
      for (int c = 0; c < 28; c += 4) *(float4*)&kv[c] = *(const float4*)(kf + c);
      float s = 0.f;
      #pragma unroll
      for (int c = 0; c < 16; ++c) s += q1s[h][c] * kv[c];
      float d2 = 0.f;
      #pragma unroll
      for (int d = 0; d < 12; ++d) { float df = qps[h][d] - kv[16+d]; d2 += df*df; }
      val[rr] = SC1_*s - WC_*d2;
    }
  }
  float4 o; o.x = val[0]; o.y = val[1]; o.z = val[2]; o.w = val[3];
  *(float4*)(ws + OFF_QKF + ((size_t)b*4 + w)*256 + l*4) = o;
}

// ============ kernel F: fused bias(MFMA) + online softmax + o_2d, one pass over rep ============
__global__ __launch_bounds__(256) void flash_kernel(
    const float* __restrict__ rep, float* __restrict__ ws) {
  const int i = blockIdx.x;
  const int t = threadIdx.x;
  const int lane = t & 63, wv = t >> 6;
  __shared__ ushort A[64 * 128];     // bf16 tile, slot-XOR swizzled (slot=16B)
  __shared__ ushort e_l[64 * 16];    // bf16 e, rows of 16 heads
  __shared__ float mt[64], est[64], fact[16], mrun[16], srun[16];

  // B-fragments (weights) for both j-sides, in registers
  const short8_m* wf = (const short8_m*)(ws + OFF_WFRAG);
  const int m0 = (i < NRR) ? 0 : 2, m1 = (i < NRR) ? 1 : 3;
  short8_m bf0[4], bf1[4];
  #pragma unroll
  for (int ks = 0; ks < 4; ++ks) {
    bf0[ks] = wf[(m0*4 + ks)*64 + lane];
    bf1[ks] = wf[(m1*4 + ks)*64 + lane];
  }
  if (t < 16) { mrun[t] = -1e30f; srun[t] = 0.f; }
  float acc[48];
  #pragma unroll
  for (int k = 0; k < 48; ++k) acc[k] = 0.f;

  const int cq = t & 31, jgr = t >> 5;        // staging / o2d roles
  const int hh = lane & 15, jq = lane >> 4;   // MFMA roles
  const int rowA = wv*16 + hh;                // A-frag row for this lane
  __syncthreads();

  for (int tile = 0; tile < 12; ++tile) {
    // ---- stage rep tile -> bf16 LDS (swizzled) ----
    const float* src = rep + ((size_t)i*N_ + tile*64) * C2_;
    #pragma unroll
    for (int k = 0; k < 8; ++k) {
      int j = jgr + k*8;
      float4 v = *(const float4*)(src + j*C2_ + cq*4);
      uint2 p;
      p.x = (uint)f2bf(v.x) | ((uint)f2bf(v.y) << 16);
      p.y = (uint)f2bf(v.z) | ((uint)f2bf(v.w) << 16);
      int slot = (cq >> 1) ^ (j & 7);
      *(uint2*)((char*)A + j*256 + slot*16 + (cq & 1)*8) = p;
    }
    __syncthreads();

    // ---- bias GEMM: C[16j x 16h] per wave ----
    f32x4_m c4 = {0.f, 0.f, 0.f, 0.f};
    #pragma unroll
    for (int ks = 0; ks < 4; ++ks) {
      int slot = (ks*4 + jq) ^ (rowA & 7);
      short8_m a = *(const short8_m*)((const char*)A + rowA*256 + slot*16);
      c4 = __builtin_amdgcn_mfma_f32_16x16x32_bf16(
          a, (tile < 8) ? bf0[ks] : bf1[ks], c4, 0, 0, 0);
    }
    float4 qk4 = *(const float4*)(ws + OFF_QKF +
        (((size_t)i*12 + tile)*4 + wv)*256 + lane*4);
    float aff0 = c4[0] + qk4.x, aff1 = c4[1] + qk4.y;
    float aff2 = c4[2] + qk4.z, aff3 = c4[3] + qk4.w;

    // per-head max over this tile (column hh)
    float ml = fmaxf(fmaxf(aff0, aff1), fmaxf(aff2, aff3));
    ml = fmaxf(ml, __shfl_xor(ml, 16));
    ml = fmaxf(ml, __shfl_xor(ml, 32));
    if (jq == 0) mt[wv*16 + hh] = ml;
    __syncthreads();
    if (t < 12) {
      float m4 = fmaxf(fmaxf(mt[t], mt[16+t]), fmaxf(mt[32+t], mt[48+t]));
      float mn = fmaxf(mrun[t], m4);
      fact[t]  = __expf(mrun[t] - mn);
      mrun[t]  = mn;
      ws[OFF_MUSED + (size_t)i*192 + tile*16 + t] = mn;
    }
    __syncthreads();

    // ---- e = exp(aff - m), to LDS (bf16) + per-head sums ----
    const bool valid = (hh < 12);
    float mh = valid ? mrun[hh] : 0.f;
    float e0 = valid ? __expf(aff0 - mh) : 0.f;
    float e1 = valid ? __expf(aff1 - mh) : 0.f;
    float e2 = valid ? __expf(aff2 - mh) : 0.f;
    float e3 = valid ? __expf(aff3 - mh) : 0.f;
    if (valid) {
      int jb = wv*16 + jq*4;
      e_l[(jb+0)*16 + hh] = f2bf(e0);
      e_l[(jb+1)*16 + hh] = f2bf(e1);
      e_l[(jb+2)*16 + hh] = f2bf(e2);
      e_l[(jb+3)*16 + hh] = f2bf(e3);
    }
    float es = e0 + e1 + e2 + e3;
    es += __shfl_xor(es, 16);
    es += __shfl_xor(es, 32);
    if (jq == 0) est[wv*16 + hh] = es;
    __syncthreads();
    if (t < 12)
      srun[t] = srun[t]*fact[t] + (est[t] + est[16+t] + est[32+t] + est[48+t]);

    // ---- o2d accumulate (rescale then add tile) ----
    float fc[12];
    #pragma unroll
    for (int h = 0; h < 12; ++h) fc[h] = fact[h];
    #pragma unroll
    for (int h = 0; h < 12; ++h) {
      acc[h*4+0] *= fc[h]; acc[h*4+1] *= fc[h];
      acc[h*4+2] *= fc[h]; acc[h*4+3] *= fc[h];
    }
    #pragma unroll
    for (int k = 0; k < 8; ++k) {
      int j = jgr + k*8;
      const char* ep = (const char*)e_l + j*32;
      uint4 u4 = *(const uint4*)ep;
      uint2 u2 = *(const uint2*)(ep + 16);
      float ef[12];
      ef[0] = __uint_as_float(u4.x << 16); ef[1] = __uint_as_float(u4.x & 0xffff0000u);
      ef[2] = __uint_as_float(u4.y << 16); ef[3] = __uint_as_float(u4.y & 0xffff0000u);
      ef[4] = __uint_as_float(u4.z << 16); ef[5] = __uint_as_float(u4.z & 0xffff0000u);
      ef[6] = __uint_as_float(u4.w << 16); ef[7] = __uint_as_float(u4.w & 0xffff0000u);
      ef[8] = __uint_as_float(u2.x << 16); ef[9] = __uint_as_float(u2.x & 0xffff0000u);
      ef[10] = __uint_as_float(u2.y << 16); ef[11] = __uint_as_float(u2.y & 0xffff0000u);
      int slot = (cq >> 1) ^ (j & 7);
      uint2 av = *(const uint2*)((const char*)A + j*256 + slot*16 + (cq & 1)*8);
      float af[4];
      af[0] = __uint_as_float(av.x << 16); af[1] = __uint_as_float(av.x & 0xffff0000u);
      af[2] = __uint_as_float(av.y << 16); af[3] = __uint_as_float(av.y & 0xffff0000u);
      #pragma unroll
      for (int h = 0; h < 12; ++h) {
        acc[h*4+0] += ef[h]*af[0];
        acc[h*4+1] += ef[h]*af[1];
        acc[h*4+2] += ef[h]*af[2];
        acc[h*4+3] += ef[h]*af[3];
      }
    }
    // ---- write unnormalized e (f32) for the opoint kernel ----
    #pragma unroll
    for (int k = 0; k < 3; ++k) {
      int h = wv + k*4;
      ws[OFF_W + (size_t)i*9216 + h*768 + tile*64 + lane] =
          bf2f(e_l[lane*16 + h]);
    }
    __syncthreads();
  }

  if (t < 12) {
    ws[OFF_MSFIN + i*32 + t]      = mrun[t];
    ws[OFF_MSFIN + i*32 + 16 + t] = srun[t];
  }
  // ---- reduce 8 jg-partials + normalize + write feat ----
  #pragma unroll
  for (int k = 0; k < 48; ++k) acc[k] += __shfl_xor(acc[k], 32);
  float* scr = (float*)A;
  __syncthreads();
  if (wv >= 2 && lane < 32) {
    float* dst = scr + (wv-2)*1536 + lane*48;
    #pragma unroll
    for (int k = 0; k < 48; ++k) dst[k] = acc[k];
  }
  __syncthreads();
  if (wv < 2 && lane < 32) {
    const float* s2 = scr + wv*1536 + lane*48;
    #pragma unroll
    for (int k = 0; k < 48; ++k) acc[k] += s2[k];
  }
  __syncthreads();
  if (wv == 1 && lane < 32) {
    float* dst = scr + lane*48;
    #pragma unroll
    for (int k = 0; k < 48; ++k) dst[k] = acc[k];
  }
  __syncthreads();
  if (wv == 0 && lane < 32) {
    const float* s2 = scr + lane*48;
    #pragma unroll
    for (int k = 0; k < 48; ++k) acc[k] += s2[k];
    float* feat = ws + OFF_FEAT + (size_t)i*2112;
    #pragma unroll
    for (int h = 0; h < 12; ++h) {
      float inv = 1.0f / srun[h];
      float4 r;
      r.x = acc[h*4+0]*inv; r.y = acc[h*4+1]*inv;
      r.z = acc[h*4+2]*inv; r.w = acc[h*4+3]*inv;
      *(float4*)&feat[h*128 + lane*4] = r;
    }
  }
}

// ========= kernel E: point outputs + o_1d + o_pt + o_norm =========
__global__ __launch_bounds__(320) void opoint_kernel(
    const float* __restrict__ ws_w, const float* __restrict__ vp,
    const float* __restrict__ R, const float* __restrict__ tvec,
    const float* __restrict__ v1, const float* __restrict__ mused,
    const float* __restrict__ msfin, float* __restrict__ feat) {
  const int i = blockIdx.x;
  const int tid = threadIdx.x;   // 320
  __shared__ float wl[H_ * N_];  // [h][j], 36 KB
  __shared__ float cf[144];      // [h][tile] normalization factors
  __shared__ float og[288];
  __shared__ float ol[288];
  if (tid < 144) {
    int h = tid / 12, tl = tid % 12;
    float sfin = msfin[i*32 + 16 + h];
    cf[tid] = __expf(mused[(size_t)i*192 + tl*16 + h] - msfin[i*32 + h]) / sfin;
  }
  __syncthreads();
  for (int k = tid; k < H_*N_; k += 320) {
    int h = k / 768, j = k - h*768;
    wl[k] = ws_w[(size_t)i*9216 + k] * cf[h*12 + (j >> 6)];
  }
  __syncthreads();
  if (tid < 288) {
    int d = tid / 96, hh = (tid % 96) / 8;
    float acc = 0.f;
    for (int j = 0; j < N_; ++j) acc += wl[hh*N_ + j] * vp[(size_t)j*288 + tid];
    og[tid] = acc - tvec[i*3 + d];
  }
  if (tid < 192) feat[(size_t)i*2112 + 1536 + tid] = v1[(size_t)i*192 + tid];
  __syncthreads();
  if (tid < 288) {
    int i3 = tid / 96, rem = tid % 96, hh = rem / 8, p = rem % 8;
    float o = R[i*9 + 0*3 + i3] * og[0*96 + rem]
            + R[i*9 + 1*3 + i3] * og[1*96 + rem]
            + R[i*9 + 2*3 + i3] * og[2*96 + rem];
    ol[tid] = o;
    feat[(size_t)i*2112 + 1728 + p*36 + hh*3 + i3] = o;
  }
  __syncthreads();
  if (tid < 96) {
    int hh = tid / 8, p = tid % 8;
    float a = ol[0*96 + tid], b = ol[1*96 + tid], c = ol[2*96 + tid];
    feat[(size_t)i*2112 + 2016 + p*12 + hh] = sqrtf(a*a + b*b + c*c);
  }
}

// ================= kernel F1: feat @ final_w partials (k-split x2) =================
__global__ __launch_bounds__(384) void final1_kernel(
    const float* __restrict__ ws, const float* __restrict__ fw,
    float* __restrict__ part) {
  const int i0 = blockIdx.x * 4;
  const int ks = blockIdx.y;
  const int o  = threadIdx.x;    // 384
  const int k0 = ks * 1056;
  __shared__ float fl[4 * 1056];
  const float* feat = ws + OFF_FEAT;
  for (int idx = o; idx < 1056; idx += 384) {
    int r = idx / 264, f4 = idx % 264;
    *(float4*)&fl[r*1056 + f4*4] =
        *(const float4*)(feat + (size_t)(i0+r)*2112 + k0 + f4*4);
  }
  __syncthreads();
  float a0=0,a1=0,a2=0,a3=0;
  for (int f4 = 0; f4 < 264; ++f4) {
    int f = k0 + f4*4;
    float w0 = fw[(size_t)(f+0)*384 + o];
    float w1 = fw[(size_t)(f+1)*384 + o];
    float w2 = fw[(size_t)(f+2)*384 + o];
    float w3 = fw[(size_t)(f+3)*384 + o];
    float4 f0 = *(const float4*)&fl[0*1056 + f4*4];
    float4 f1 = *(const float4*)&fl[1*1056 + f4*4];
    float4 f2 = *(const float4*)&fl[2*1056 + f4*4];
    float4 f3 = *(const float4*)&fl[3*1056 + f4*4];
    a0 += f0.x*w0 + f0.y*w1 + f0.z*w2 + f0.w*w3;
    a1 += f1.x*w0 + f1.y*w1 + f1.z*w2 + f1.w*w3;
    a2 += f2.x*w0 + f2.y*w1 + f2.z*w2 + f2.w*w3;
    a3 += f3.x*w0 + f3.y*w1 + f3.z*w2 + f3.w*w3;
  }
  part[((size_t)ks*N_ + i0+0)*384 + o] = a0;
  part[((size_t)ks*N_ + i0+1)*384 + o] = a1;
  part[((size_t)ks*N_ + i0+2)*384 + o] = a2;
  part[((size_t)ks*N_ + i0+3)*384 + o] = a3;
}

// ================= kernel F2: add partials + bias =================
__global__ __launch_bounds__(256) void final2_kernel(
    const float* __restrict__ part, const float* __restrict__ fb,
    float* __restrict__ out) {
  int idx = blockIdx.x * 256 + threadIdx.x;   // < 294912
  int col = idx % 384;
  out[idx] = part[idx] + part[294912 + idx] + fb[col];
}

// ================= launch =================
extern "C" void kernel_launch(void* const* d_in, const int* in_sizes, int n_in,
                              void* d_out, int out_size, void* d_ws, size_t ws_size,
                              hipStream_t stream) {
  const float* rec_1d  = (const float*)d_in[0];
  const float* lig_1d  = (const float*)d_in[1];
  const float* rep_2d  = (const float*)d_in[2];
  const float* rec_T   = (const float*)d_in[3];
  const float* lig_T   = (const float*)d_in[4];
  const float* rec_w1d = (const float*)d_in[5];
  const float* rec_wpt = (const float*)d_in[6];
  const float* lig_w1d = (const float*)d_in[7];
  const float* lig_wpt = (const float*)d_in[8];
  const float* rr_w    = (const float*)d_in[9];
  const float* ll_w    = (const float*)d_in[10];
  const float* rl_w    = (const float*)d_in[11];
  const float* lr_w    = (const float*)d_in[12];
  const float* final_w = (const float*)d_in[13];
  const float* final_b = (const float*)d_in[14];
  float* ws  = (float*)d_ws;
  float* out = (float*)d_out;

  proj_kernel<<<192, 192, 0, stream>>>(rec_1d, lig_1d, rec_T, lig_T,
                                       rec_w1d, rec_wpt, lig_w1d, lig_wpt, ws);
  wfrag_kernel<<<1, 256, 0, stream>>>(rr_w, rl_w, lr_w, ll_w, ws);
  qk_kernel<<<N_*12, 256, 0, stream>>>(ws);
  flash_kernel<<<N_, 256, 0, stream>>>(rep_2d, ws);
  opoint_kernel<<<N_, 320, 0, stream>>>(ws + OFF_W, ws + OFF_VP, ws + OFF_R,
                                        ws + OFF_T, ws + OFF_V1, ws + OFF_MUSED,
                                        ws + OFF_MSFIN, ws + OFF_FEAT);
  final1_kernel<<<dim3(N_/4, 2), 384, 0, stream>>>(ws, final_w, ws + OFF_PART);
  final2_kernel<<<1152, 256, 0, stream>>>(ws + OFF_PART, final_b, out);
}

// Round 7
// 892.733 us; speedup vs baseline: 1.1051x; 1.1051x over previous
//
#include <hip/hip_runtime.h>
#include <math.h>

// ---------------- problem constants ----------------
#define H_   12
#define NRR  512
#define N_   768
#define C1_  384
#define C2_  128
#define SPLIT 3
#define TPB  4   // tiles per block (12/SPLIT)
static __device__ __constant__ float WC_  = 0.2357022603955158f;   // sqrt(2/(9*4))
static __device__ __constant__ float SC1_ = 0.14433756729740646f;  // sqrt(1/3)/sqrt(16)

// ---------------- workspace layout (float offsets), ~88.7 MiB ----------------
#define OFF_Q1     0            // [768][12][16]
#define OFF_QP     147456       // [768][12][12]
#define OFF_V1     258048       // [768][12][16]
#define OFF_VP     405504       // [768][3][96]   ([j][d][h*8+p])
#define OFF_R      626688       // [768][9]
#define OFF_T      633600       // [768][3]
#define OFF_KHAT   635904       // [12][768][32]  (0..15 k1, 16..27 kp)
#define OFF_WFRAG  930816       // 4 mats x 4 ks x 64 lanes x 8 bf16 (as 4096 floats)
#define OFF_QKF    934912       // [768*12 tiles][4 w][64 lane][4 reg] f32
#define OFF_SSP    10372096     // [3][768][16] partial sums of e
#define OFF_SSUM   10408960     // [768][16]  1/s per head
#define OFF_O2DP   10421248     // [3][768][1536] partial o2d
#define OFF_W      13960192     // [768][12 h][768 j]  unnormalized e (f32), m=0
#define OFF_FEAT   21038080     // [768][2112]
#define OFF_PART   22660096     // [2][768][384]

typedef __attribute__((ext_vector_type(8))) short short8_m;
typedef __attribute__((ext_vector_type(4))) float f32x4_m;

__device__ __forceinline__ ushort f2bf(float f) {
  uint u = __float_as_uint(f);
  uint r = (u + 0x7fffu + ((u >> 16) & 1u)) >> 16;
  return (ushort)r;
}
__device__ __forceinline__ float bf2f(ushort v) {
  return __uint_as_float(((uint)v) << 16);
}

// raw barrier: drain LDS ops but let global loads stay in flight (T3/T4)
#define BARRAW() do {                                        \
    asm volatile("s_waitcnt lgkmcnt(0)" ::: "memory");       \
    __builtin_amdgcn_s_barrier();                            \
    __builtin_amdgcn_sched_barrier(0);                       \
  } while (0)

// ================= kernel A: per-token projections =================
__global__ __launch_bounds__(192) void proj_kernel(
    const float* __restrict__ rec_1d, const float* __restrict__ lig_1d,
    const float* __restrict__ rec_T,  const float* __restrict__ lig_T,
    const float* __restrict__ rec_w1d, const float* __restrict__ rec_wpt,
    const float* __restrict__ lig_w1d, const float* __restrict__ lig_wpt,
    float* __restrict__ ws) {
  const int tok0 = blockIdx.x * 4;
  const int tid  = threadIdx.x;       // 0..191
  __shared__ float xs[4][384];
  __shared__ float loc[4][576];
  __shared__ float Rs[4][9];
  __shared__ float tts[4][3];

  for (int r = 0; r < 4; ++r) {
    int n = tok0 + r;
    const float* x = (n < NRR) ? rec_1d + n * C1_ : lig_1d + (n - NRR) * C1_;
    for (int k = tid; k < C1_; k += 192) xs[r][k] = x[k];
  }
  if (tid < 4) {
    int n = tok0 + tid;
    const float* T = (n < NRR) ? rec_T + n * 7 : lig_T + (n - NRR) * 7;
    float qw = T[0], qx = T[1], qy = T[2], qz = T[3];
    float inv = 1.0f / sqrtf(qw*qw + qx*qx + qy*qy + qz*qz);
    qw *= inv; qx *= inv; qy *= inv; qz *= inv;
    Rs[tid][0] = 1.f - 2.f*(qy*qy + qz*qz);
    Rs[tid][1] = 2.f*(qx*qy - qw*qz);
    Rs[tid][2] = 2.f*(qx*qz + qw*qy);
    Rs[tid][3] = 2.f*(qx*qy + qw*qz);
    Rs[tid][4] = 1.f - 2.f*(qx*qx + qz*qz);
    Rs[tid][5] = 2.f*(qy*qz - qw*qx);
    Rs[tid][6] = 2.f*(qx*qz - qw*qy);
    Rs[tid][7] = 2.f*(qy*qz + qw*qx);
    Rs[tid][8] = 1.f - 2.f*(qx*qx + qy*qy);
    tts[tid][0] = T[4]; tts[tid][1] = T[5]; tts[tid][2] = T[6];
    float* Rg = ws + OFF_R + n * 9;
    #pragma unroll
    for (int k = 0; k < 9; ++k) Rg[k] = Rs[tid][k];
    float* tg = ws + OFF_T + n * 3;
    tg[0] = T[4]; tg[1] = T[5]; tg[2] = T[6];
  }
  __syncthreads();

  const float* w1 = (tok0 < NRR) ? rec_w1d : lig_w1d;
  const float* w2 = (tok0 < NRR) ? rec_wpt : lig_wpt;
  for (int cc = 0; cc < 3; ++cc) {
    int c = tid + cc * 192;
    float a0=0,a1=0,a2=0,a3=0,b0=0,b1=0,b2=0,b3=0;
    for (int k = 0; k < C1_; ++k) {
      float wv = w1[k * 576 + c];
      float wp = w2[k * 576 + c];
      float x0 = xs[0][k], x1 = xs[1][k], x2 = xs[2][k], x3 = xs[3][k];
      a0 += x0*wv; a1 += x1*wv; a2 += x2*wv; a3 += x3*wv;
      b0 += x0*wp; b1 += x1*wp; b2 += x2*wp; b3 += x3*wp;
    }
    loc[0][c]=b0; loc[1][c]=b1; loc[2][c]=b2; loc[3][c]=b3;
    int h = c / 48, e = c % 48;
    float av[4] = {a0,a1,a2,a3};
    for (int r = 0; r < 4; ++r) {
      int n = tok0 + r;
      if (e < 16)      ws[OFF_KHAT + ((size_t)h*N_ + n)*32 + e] = av[r];
      else if (e < 32) ws[OFF_Q1 + n*192 + h*16 + (e-16)]       = av[r];
      else             ws[OFF_V1 + n*192 + h*16 + (e-32)]       = av[r];
    }
  }
  __syncthreads();

  {
    int cp = tid;                 // 0..191
    int h = cp >> 4, e = cp & 15;
    for (int r = 0; r < 4; ++r) {
      int n = tok0 + r;
      float g[3];
      #pragma unroll
      for (int d = 0; d < 3; ++d)
        g[d] = Rs[r][d*3+0]*loc[r][cp] + Rs[r][d*3+1]*loc[r][192+cp]
             + Rs[r][d*3+2]*loc[r][384+cp] + tts[r][d];
      if (e < 4) {
        #pragma unroll
        for (int d = 0; d < 3; ++d)
          ws[OFF_KHAT + ((size_t)h*N_ + n)*32 + 16 + e*3 + d] = g[d];
      } else if (e < 8) {
        #pragma unroll
        for (int d = 0; d < 3; ++d) ws[OFF_QP + n*144 + h*12 + (e-4)*3 + d] = g[d];
      } else {
        #pragma unroll
        for (int d = 0; d < 3; ++d) ws[OFF_VP + n*288 + d*96 + h*8 + (e-8)] = g[d];
      }
    }
  }
}

// ============ kernel W: build bf16 MFMA B-fragments of the 4 bias weights ============
__global__ __launch_bounds__(256) void wfrag_kernel(
    const float* __restrict__ rr_w, const float* __restrict__ rl_w,
    const float* __restrict__ lr_w, const float* __restrict__ ll_w,
    float* __restrict__ ws) {
  ushort* wf = (ushort*)(ws + OFF_WFRAG);
  const float* mats[4] = { rr_w, rl_w, lr_w, ll_w };
  for (int idx = threadIdx.x; idx < 8192; idx += 256) {
    int mat = idx >> 11;
    int r   = idx & 2047;
    int ks  = r >> 9;
    int r2  = r & 511;
    int l   = r2 >> 3;
    int e   = r2 & 7;
    int n   = l & 15;
    int k   = ks*32 + (l>>4)*8 + e;
    float v = (n < 12) ? mats[mat][k*12 + n] : 0.f;
    wf[idx] = f2bf(v);
  }
}

// ============ kernel QK: scalar-q·k + point-distance terms, fragment-ordered ============
__global__ __launch_bounds__(256) void qk_kernel(float* __restrict__ ws) {
  const int b = blockIdx.x;
  const int i = b / 12, tile = b % 12;
  const int t = threadIdx.x;
  const int l = t & 63, w = t >> 6;
  __shared__ float q1s[12][16];
  __shared__ float qps[12][12];
  if (t < 192) q1s[t >> 4][t & 15] = ws[OFF_Q1 + i*192 + t];
  if (t < 144) qps[t / 12][t % 12] = ws[OFF_QP + i*144 + t];
  __syncthreads();
  const int h = l & 15, jq = l >> 4;
  float val[4] = {0.f, 0.f, 0.f, 0.f};
  if (h < 12) {
    #pragma unroll
    for (int rr = 0; rr < 4; ++rr) {
      int j = tile*64 + w*16 + jq*4 + rr;
      const float* kf = ws + OFF_KHAT + ((size_t)h*N_ + j)*32;
      float kv[28];
      #pragma unroll
      for (int c = 0; c < 28; c += 4) *(float4*)&kv[c] = *(const float4*)(kf + c);
      float s = 0.f;
      #pragma unroll
      for (int c = 0; c < 16; ++c) s += q1s[h][c] * kv[c];
      float d2 = 0.f;
      #pragma unroll
      for (int d = 0; d < 12; ++d) { float df = qps[h][d] - kv[16+d]; d2 += df*df; }
      val[rr] = SC1_*s - WC_*d2;
    }
  }
  float4 o; o.x = val[0]; o.y = val[1]; o.z = val[2]; o.w = val[3];
  *(float4*)(ws + OFF_QKF + ((size_t)b*4 + w)*256 + l*4) = o;
}

// ============ kernel F: fused bias(MFMA) + exp (m=0) + partial o_2d ============
// grid 2304: block (i, sp) handles tiles sp*4 .. sp*4+3. No online max (m=0 safe
// for this data scale: aff <= ~+3). Raw barriers keep prefetch loads in flight.
__global__ __launch_bounds__(256) void flash_kernel(
    const float* __restrict__ rep, float* __restrict__ ws) {
  const int b = blockIdx.x;
  const int i = b / SPLIT, sp = b % SPLIT;
  const int t0 = sp * TPB;
  const int t = threadIdx.x;
  const int lane = t & 63, wv = t >> 6;
  __shared__ ushort A[2][64 * 128];   // bf16 tiles, slot-XOR swizzled, double buffered
  __shared__ ushort e_l[64 * 16];     // bf16 e, rows of 16 heads

  // B-fragment (weights): one matrix per block (tile range is on one j-side)
  const short8_m* wf = (const short8_m*)(ws + OFF_WFRAG);
  const int m = ((i < NRR) ? 0 : 2) + ((t0 >= 8) ? 1 : 0);
  short8_m bfr[4];
  #pragma unroll
  for (int ks = 0; ks < 4; ++ks) bfr[ks] = wf[(m*4 + ks)*64 + lane];

  // qk terms for all TPB tiles, prefetched
  float4 qk4pf[TPB];
  #pragma unroll
  for (int tt = 0; tt < TPB; ++tt)
    qk4pf[tt] = *(const float4*)(ws + OFF_QKF +
        (((size_t)i*12 + t0 + tt)*4 + wv)*256 + lane*4);

  float acc[48];
  #pragma unroll
  for (int k = 0; k < 48; ++k) acc[k] = 0.f;
  float ssum[12];
  #pragma unroll
  for (int h = 0; h < 12; ++h) ssum[h] = 0.f;

  const int cq = t & 31, jgr = t >> 5;        // staging / o2d roles
  const int hh = lane & 15, jq = lane >> 4;   // MFMA roles
  const int rowA = wv*16 + hh;                // A-frag row for this lane

  // ---- prologue: stage tile t0 into A[0] ----
  float4 pf[8];
  {
    const float* src = rep + ((size_t)i*N_ + t0*64) * C2_;
    #pragma unroll
    for (int k = 0; k < 8; ++k)
      pf[k] = *(const float4*)(src + (jgr + k*8)*C2_ + cq*4);
    #pragma unroll
    for (int k = 0; k < 8; ++k) {
      int j = jgr + k*8;
      uint2 p;
      p.x = (uint)f2bf(pf[k].x) | ((uint)f2bf(pf[k].y) << 16);
      p.y = (uint)f2bf(pf[k].z) | ((uint)f2bf(pf[k].w) << 16);
      int slot = (cq >> 1) ^ (j & 7);
      *(uint2*)((char*)A[0] + j*256 + slot*16 + (cq & 1)*8) = p;
    }
  }
  BARRAW();

  int cur = 0;
  for (int tt = 0; tt < TPB; ++tt) {
    const int tile = t0 + tt;
    // ---- issue prefetch for next tile (stays in flight across barriers) ----
    if (tt < TPB-1) {
      const float* src = rep + ((size_t)i*N_ + (tile+1)*64) * C2_;
      #pragma unroll
      for (int k = 0; k < 8; ++k)
        pf[k] = *(const float4*)(src + (jgr + k*8)*C2_ + cq*4);
    }

    // ---- bias GEMM: C[16j x 16h] per wave ----
    f32x4_m c4 = {0.f, 0.f, 0.f, 0.f};
    #pragma unroll
    for (int ks = 0; ks < 4; ++ks) {
      int slot = (ks*4 + jq) ^ (rowA & 7);
      short8_m a = *(const short8_m*)((const char*)A[cur] + rowA*256 + slot*16);
      c4 = __builtin_amdgcn_mfma_f32_16x16x32_bf16(a, bfr[ks], c4, 0, 0, 0);
    }
    // ---- e = exp(aff) with m = 0 ----
    float e0 = __expf(c4[0] + qk4pf[tt].x);
    float e1 = __expf(c4[1] + qk4pf[tt].y);
    float e2 = __expf(c4[2] + qk4pf[tt].z);
    float e3 = __expf(c4[3] + qk4pf[tt].w);
    if (hh < 12) {
      int jb = wv*16 + jq*4;
      e_l[(jb+0)*16 + hh] = f2bf(e0);
      e_l[(jb+1)*16 + hh] = f2bf(e1);
      e_l[(jb+2)*16 + hh] = f2bf(e2);
      e_l[(jb+3)*16 + hh] = f2bf(e3);
    }
    BARRAW();   // e_l visible; prefetch loads still in flight

    // ---- o2d + ssum accumulate; write unnormalized e to OFF_W ----
    #pragma unroll
    for (int k = 0; k < 8; ++k) {
      int j = jgr + k*8;
      const char* ep = (const char*)e_l + j*32;
      uint4 u4 = *(const uint4*)ep;
      uint2 u2 = *(const uint2*)(ep + 16);
      float ef[12];
      ef[0] = __uint_as_float(u4.x << 16); ef[1] = __uint_as_float(u4.x & 0xffff0000u);
      ef[2] = __uint_as_float(u4.y << 16); ef[3] = __uint_as_float(u4.y & 0xffff0000u);
      ef[4] = __uint_as_float(u4.z << 16); ef[5] = __uint_as_float(u4.z & 0xffff0000u);
      ef[6] = __uint_as_float(u4.w << 16); ef[7] = __uint_as_float(u4.w & 0xffff0000u);
      ef[8] = __uint_as_float(u2.x << 16); ef[9] = __uint_as_float(u2.x & 0xffff0000u);
      ef[10] = __uint_as_float(u2.y << 16); ef[11] = __uint_as_float(u2.y & 0xffff0000u);
      int slot = (cq >> 1) ^ (j & 7);
      uint2 av = *(const uint2*)((const char*)A[cur] + j*256 + slot*16 + (cq & 1)*8);
      float af[4];
      af[0] = __uint_as_float(av.x << 16); af[1] = __uint_as_float(av.x & 0xffff0000u);
      af[2] = __uint_as_float(av.y << 16); af[3] = __uint_as_float(av.y & 0xffff0000u);
      #pragma unroll
      for (int h = 0; h < 12; ++h) {
        acc[h*4+0] += ef[h]*af[0];
        acc[h*4+1] += ef[h]*af[1];
        acc[h*4+2] += ef[h]*af[2];
        acc[h*4+3] += ef[h]*af[3];
        ssum[h] += ef[h];
      }
    }
    #pragma unroll
    for (int k = 0; k < 3; ++k) {
      int h = wv + k*4;
      ws[OFF_W + (size_t)i*9216 + h*768 + tile*64 + lane] =
          bf2f(e_l[lane*16 + h]);
    }
    // ---- stage next tile into the other LDS buffer (vmcnt wait lands here) ----
    if (tt < TPB-1) {
      #pragma unroll
      for (int k = 0; k < 8; ++k) {
        int j = jgr + k*8;
        uint2 p;
        p.x = (uint)f2bf(pf[k].x) | ((uint)f2bf(pf[k].y) << 16);
        p.y = (uint)f2bf(pf[k].z) | ((uint)f2bf(pf[k].w) << 16);
        int slot = (cq >> 1) ^ (j & 7);
        *(uint2*)((char*)A[cur^1] + j*256 + slot*16 + (cq & 1)*8) = p;
      }
    }
    BARRAW();
    cur ^= 1;
  }

  // ---- reduce 8 jgr-partials of acc[48] + ssum[12]; write partials ----
  #pragma unroll
  for (int k = 0; k < 48; ++k) acc[k] += __shfl_xor(acc[k], 32);
  #pragma unroll
  for (int h = 0; h < 12; ++h) ssum[h] += __shfl_xor(ssum[h], 32);
  float* scr = (float*)A;    // 8192 floats available
  __syncthreads();
  if (wv >= 2 && lane < 32) {
    float* dst = scr + (wv-2)*1920 + lane*60;
    #pragma unroll
    for (int k = 0; k < 48; ++k) dst[k] = acc[k];
    #pragma unroll
    for (int h = 0; h < 12; ++h) dst[48+h] = ssum[h];
  }
  __syncthreads();
  if (wv < 2 && lane < 32) {
    const float* s2 = scr + wv*1920 + lane*60;
    #pragma unroll
    for (int k = 0; k < 48; ++k) acc[k] += s2[k];
    #pragma unroll
    for (int h = 0; h < 12; ++h) ssum[h] += s2[48+h];
  }
  __syncthreads();
  if (wv == 1 && lane < 32) {
    float* dst = scr + lane*60;
    #pragma unroll
    for (int k = 0; k < 48; ++k) dst[k] = acc[k];
    #pragma unroll
    for (int h = 0; h < 12; ++h) dst[48+h] = ssum[h];
  }
  __syncthreads();
  if (wv == 0 && lane < 32) {
    const float* s2 = scr + lane*60;
    #pragma unroll
    for (int k = 0; k < 48; ++k) acc[k] += s2[k];
    #pragma unroll
    for (int h = 0; h < 12; ++h) ssum[h] += s2[48+h];
    float* part = ws + OFF_O2DP + ((size_t)sp*N_ + i)*1536;
    #pragma unroll
    for (int h = 0; h < 12; ++h) {
      float4 r;
      r.x = acc[h*4+0]; r.y = acc[h*4+1]; r.z = acc[h*4+2]; r.w = acc[h*4+3];
      *(float4*)&part[h*128 + lane*4] = r;
    }
    if (lane == 0) {
      #pragma unroll
      for (int h = 0; h < 12; ++h)
        ws[OFF_SSP + ((size_t)sp*N_ + i)*16 + h] = ssum[h];
    }
  }
}

// ============ kernel C2: combine partials, normalize o_2d, store 1/s ============
__global__ __launch_bounds__(256) void o2dfin_kernel(float* __restrict__ ws) {
  const int i = blockIdx.x;
  const int t = threadIdx.x;
  __shared__ float inv_s[12];
  if (t < 12) {
    float s = ws[OFF_SSP + (size_t)i*16 + t]
            + ws[OFF_SSP + ((size_t)N_ + i)*16 + t]
            + ws[OFF_SSP + ((size_t)2*N_ + i)*16 + t];
    float inv = 1.0f / s;
    inv_s[t] = inv;
    ws[OFF_SSUM + i*16 + t] = inv;
  }
  __syncthreads();
  #pragma unroll
  for (int k = 0; k < 6; ++k) {
    int idx = t + k*256;            // 0..1535
    int h = idx >> 7;
    float v = ws[OFF_O2DP + (size_t)i*1536 + idx]
            + ws[OFF_O2DP + ((size_t)N_ + i)*1536 + idx]
            + ws[OFF_O2DP + ((size_t)2*N_ + i)*1536 + idx];
    ws[OFF_FEAT + (size_t)i*2112 + idx] = v * inv_s[h];
  }
}

// ========= kernel E: point outputs + o_1d + o_pt + o_norm =========
__global__ __launch_bounds__(320) void opoint_kernel(
    const float* __restrict__ ws_w, const float* __restrict__ vp,
    const float* __restrict__ R, const float* __restrict__ tvec,
    const float* __restrict__ v1, const float* __restrict__ invs,
    float* __restrict__ feat) {
  const int i = blockIdx.x;
  const int tid = threadIdx.x;   // 320
  __shared__ float wl[H_ * N_];  // [h][j], 36 KB
  __shared__ float iv[12];
  __shared__ float og[288];
  __shared__ float ol[288];
  if (tid < 12) iv[tid] = invs[i*16 + tid];
  __syncthreads();
  for (int k = tid; k < H_*N_; k += 320) {
    int h = k / 768;
    wl[k] = ws_w[(size_t)i*9216 + k] * iv[h];
  }
  __syncthreads();
  if (tid < 288) {
    int d = tid / 96, hh = (tid % 96) / 8;
    float acc = 0.f;
    #pragma unroll 8
    for (int j = 0; j < N_; ++j) acc += wl[hh*N_ + j] * vp[(size_t)j*288 + tid];
    og[tid] = acc - tvec[i*3 + d];
  }
  if (tid < 192) feat[(size_t)i*2112 + 1536 + tid] = v1[(size_t)i*192 + tid];
  __syncthreads();
  if (tid < 288) {
    int i3 = tid / 96, rem = tid % 96, hh = rem / 8, p = rem % 8;
    float o = R[i*9 + 0*3 + i3] * og[0*96 + rem]
            + R[i*9 + 1*3 + i3] * og[1*96 + rem]
            + R[i*9 + 2*3 + i3] * og[2*96 + rem];
    ol[tid] = o;
    feat[(size_t)i*2112 + 1728 + p*36 + hh*3 + i3] = o;
  }
  __syncthreads();
  if (tid < 96) {
    int hh = tid / 8, p = tid % 8;
    float a = ol[0*96 + tid], b = ol[1*96 + tid], c = ol[2*96 + tid];
    feat[(size_t)i*2112 + 2016 + p*12 + hh] = sqrtf(a*a + b*b + c*c);
  }
}

// ================= kernel F1: feat @ final_w partials (k-split x2) =================
__global__ __launch_bounds__(384) void final1_kernel(
    const float* __restrict__ ws, const float* __restrict__ fw,
    float* __restrict__ part) {
  const int i0 = blockIdx.x * 4;
  const int ks = blockIdx.y;
  const int o  = threadIdx.x;    // 384
  const int k0 = ks * 1056;
  __shared__ float fl[4 * 1056];
  const float* feat = ws + OFF_FEAT;
  for (int idx = o; idx < 1056; idx += 384) {
    int r = idx / 264, f4 = idx % 264;
    *(float4*)&fl[r*1056 + f4*4] =
        *(const float4*)(feat + (size_t)(i0+r)*2112 + k0 + f4*4);
  }
  __syncthreads();
  float a0=0,a1=0,a2=0,a3=0;
  for (int f4 = 0; f4 < 264; ++f4) {
    int f = k0 + f4*4;
    float w0 = fw[(size_t)(f+0)*384 + o];
    float w1 = fw[(size_t)(f+1)*384 + o];
    float w2 = fw[(size_t)(f+2)*384 + o];
    float w3 = fw[(size_t)(f+3)*384 + o];
    float4 f0 = *(const float4*)&fl[0*1056 + f4*4];
    float4 f1 = *(const float4*)&fl[1*1056 + f4*4];
    float4 f2 = *(const float4*)&fl[2*1056 + f4*4];
    float4 f3 = *(const float4*)&fl[3*1056 + f4*4];
    a0 += f0.x*w0 + f0.y*w1 + f0.z*w2 + f0.w*w3;
    a1 += f1.x*w0 + f1.y*w1 + f1.z*w2 + f1.w*w3;
    a2 += f2.x*w0 + f2.y*w1 + f2.z*w2 + f2.w*w3;
    a3 += f3.x*w0 + f3.y*w1 + f3.z*w2 + f3.w*w3;
  }
  part[((size_t)ks*N_ + i0+0)*384 + o] = a0;
  part[((size_t)ks*N_ + i0+1)*384 + o] = a1;
  part[((size_t)ks*N_ + i0+2)*384 + o] = a2;
  part[((size_t)ks*N_ + i0+3)*384 + o] = a3;
}

// ================= kernel F2: add partials + bias =================
__global__ __launch_bounds__(256) void final2_kernel(
    const float* __restrict__ part, const float* __restrict__ fb,
    float* __restrict__ out) {
  int idx = blockIdx.x * 256 + threadIdx.x;   // < 294912
  int col = idx % 384;
  out[idx] = part[idx] + part[294912 + idx] + fb[col];
}

// ================= launch =================
extern "C" void kernel_launch(void* const* d_in, const int* in_sizes, int n_in,
                              void* d_out, int out_size, void* d_ws, size_t ws_size,
                              hipStream_t stream) {
  const float* rec_1d  = (const float*)d_in[0];
  const float* lig_1d  = (const float*)d_in[1];
  const float* rep_2d  = (const float*)d_in[2];
  const float* rec_T   = (const float*)d_in[3];
  const float* lig_T   = (const float*)d_in[4];
  const float* rec_w1d = (const float*)d_in[5];
  const float* rec_wpt = (const float*)d_in[6];
  const float* lig_w1d = (const float*)d_in[7];
  const float* lig_wpt = (const float*)d_in[8];
  const float* rr_w    = (const float*)d_in[9];
  const float* ll_w    = (const float*)d_in[10];
  const float* rl_w    = (const float*)d_in[11];
  const float* lr_w    = (const float*)d_in[12];
  const float* final_w = (const float*)d_in[13];
  const float* final_b = (const float*)d_in[14];
  float* ws  = (float*)d_ws;
  float* out = (float*)d_out;

  proj_kernel<<<192, 192, 0, stream>>>(rec_1d, lig_1d, rec_T, lig_T,
                                       rec_w1d, rec_wpt, lig_w1d, lig_wpt, ws);
  wfrag_kernel<<<1, 256, 0, stream>>>(rr_w, rl_w, lr_w, ll_w, ws);
  qk_kernel<<<N_*12, 256, 0, stream>>>(ws);
  flash_kernel<<<N_*SPLIT, 256, 0, stream>>>(rep_2d, ws);
  o2dfin_kernel<<<N_, 256, 0, stream>>>(ws);
  opoint_kernel<<<N_, 320, 0, stream>>>(ws + OFF_W, ws + OFF_VP, ws + OFF_R,
                                        ws + OFF_T, ws + OFF_V1, ws + OFF_SSUM,
                                        ws + OFF_FEAT);
  final1_kernel<<<dim3(N_/4, 2), 384, 0, stream>>>(ws, final_w, ws + OFF_PART);
  final2_kernel<<<1152, 256, 0, stream>>>(ws + OFF_PART, final_b, out);
}